// Round 6
// baseline (189.311 us; speedup 1.0000x reference)
//
#include <hip/hip_runtime.h>
#include <math.h>

typedef unsigned short u16;
typedef unsigned int   u32;

#define OUTSZ 7
#define B_ 2
#define C_ 256
#define R_ 256
#define N_ (B_ * R_)

// NHWC bf16 scratch: pixel index -> 256 bf16 channels (512B records).
// per-batch level pixel bases: L0:0 L1:80000 L2:100000 L3:105000 (b-major within level)
#define PX_TOTAL 106250
#define WS_INFO_OFF 0
#define WS_NHWC_OFF (512 * 1024)
#define WS_NEEDED (WS_NHWC_OFF + (size_t)PX_TOTAL * 256 * 2)

// LDS px-stride: 262 u16 = 524 B = 131 dwords (odd) -> store-phase reads hit all 32 banks
#define TSTR 262

struct RoiInfo2 {
    int pxBase, W;
    float wy0[14], wy1[14], wx0[14], wx1[14];  // valid mask folded in
    short yl[14], yh[14], xl[14], xh[14];      // absolute feature coords
};

__device__ __forceinline__ u16 f2bf(float v) {
    u32 u = __float_as_uint(v);
    u += 0x7fffu + ((u >> 16) & 1u);           // RNE to bf16
    return (u16)(u >> 16);
}

// ---------------- prep: per-ROI bilinear tables ----------------
__global__ __launch_bounds__(256) void roi_prep(const float* __restrict__ boxes,
                                                RoiInfo2* __restrict__ info)
{
    int n = blockIdx.x * 256 + threadIdx.x;
    if (n >= N_) return;

    const float* bx = boxes + (size_t)n * 4;
    float x1 = bx[0], y1 = bx[1], x2 = bx[2], y2 = bx[3];
    float area = (x2 - x1) * (y2 - y1);
    float lf = floorf(4.0f + log2f(sqrtf(area) / 224.0f + 1e-8f));
    lf = fminf(fmaxf(lf, 2.0f), 5.0f);
    int lvl = (int)lf - 2;

    const float scales[4] = {0.25f, 0.125f, 0.0625f, 0.03125f};
    const int   sizes[4]  = {200, 100, 50, 25};
    const int   bases[4]  = {0, 80000, 100000, 105000};
    float scale = scales[lvl];
    int   HW    = sizes[lvl];
    int   b     = n >> 8;

    float fx1 = x1 * scale, fy1 = y1 * scale;
    float roi_w = fmaxf(x2 * scale - fx1, 1.0f);
    float roi_h = fmaxf(y2 * scale - fy1, 1.0f);
    float bw = roi_w / (float)OUTSZ;
    float bh = roi_h / (float)OUTSZ;

    RoiInfo2 ri;
    ri.W = HW;
    ri.pxBase = bases[lvl] + b * HW * HW;

    float lim = (float)HW, cap = lim - 1.0f;
    #pragma unroll
    for (int i = 0; i < 14; ++i) {
        float g = (float)(i >> 1) + ((float)(i & 1) + 0.5f) * 0.5f;
        {   // y (torchvision aligned=False _prep)
            float c = fy1 + bh * g;
            bool  v = (c > -1.0f) && (c < lim);
            float cc = fmaxf(c, 0.0f);
            float low = floorf(cc);
            bool  edge = low >= cap;
            low = fminf(low, cap);
            float high = fminf(low + 1.0f, cap);
            float fr = edge ? 0.0f : (cc - low);
            ri.yl[i] = (short)(int)low;
            ri.yh[i] = (short)(int)high;
            ri.wy0[i] = v ? (1.0f - fr) : 0.0f;
            ri.wy1[i] = v ? fr : 0.0f;
        }
        {   // x
            float c = fx1 + bw * g;
            bool  v = (c > -1.0f) && (c < lim);
            float cc = fmaxf(c, 0.0f);
            float low = floorf(cc);
            bool  edge = low >= cap;
            low = fminf(low, cap);
            float high = fminf(low + 1.0f, cap);
            float fr = edge ? 0.0f : (cc - low);
            ri.xl[i] = (short)(int)low;
            ri.xh[i] = (short)(int)high;
            ri.wx0[i] = v ? (1.0f - fr) : 0.0f;
            ri.wx1[i] = v ? fr : 0.0f;
        }
    }
    info[n] = ri;
}

// ---------------- NCHW fp32 -> NHWC bf16: block-cooperative 64ch x 256px tile ----
// Load phase: explicit float4 r[16] batch -> 16 global_load_dwordx4 in flight
// per thread (MLP), then convert + 2x ds_write_b32 (2-way alias, free).
// Store phase: ushort2 px-pair LDS reads (stride 131 dwords -> all 32 banks,
// conflict-free), assemble two uint4 = two 128B-segment stores.
__global__ __launch_bounds__(256) void nhwc_cast(
    const float* __restrict__ f0, const float* __restrict__ f1,
    const float* __restrict__ f2, const float* __restrict__ f3,
    u16* __restrict__ dst)
{
    __shared__ u16 T[64 * TSTR];
    const int tid  = threadIdx.x;
    const int lane = tid & 63;
    const int wave = tid >> 6;

    const int t  = blockIdx.x;
    const int cb = blockIdx.y;
    const int b  = blockIdx.z;
    const float* src; int HWsz, dstBase, ft;
    if      (t < 157) { src = f0; HWsz = 40000; dstBase = 0;      ft = t;       }
    else if (t < 197) { src = f1; HWsz = 10000; dstBase = 80000;  ft = t - 157; }
    else if (t < 207) { src = f2; HWsz = 2500;  dstBase = 100000; ft = t - 197; }
    else              { src = f3; HWsz = 625;   dstBase = 105000; ft = t - 207; }

    const int fbase = ft * 256;
    const int c0    = cb * 64;
    const int rem   = HWsz - fbase;            // >= 1
    const int p0    = 4 * lane;
    const bool vec  = ((HWsz & 3) == 0) && (p0 + 3 < rem);

    // ---- load phase: batch all 16 loads before any LDS write ----
    float4 r[16];
    #pragma unroll
    for (int i = 0; i < 16; ++i) {
        const int ch = i * 4 + wave;
        const float* row = src + ((size_t)(b * C_ + c0 + ch)) * HWsz + fbase;
        if (vec) {
            r[i] = *(const float4*)(row + p0);
        } else {
            r[i].x = (p0 + 0 < rem) ? row[p0 + 0] : 0.0f;
            r[i].y = (p0 + 1 < rem) ? row[p0 + 1] : 0.0f;
            r[i].z = (p0 + 2 < rem) ? row[p0 + 2] : 0.0f;
            r[i].w = (p0 + 3 < rem) ? row[p0 + 3] : 0.0f;
        }
    }
    #pragma unroll
    for (int i = 0; i < 16; ++i) {
        const int ch = i * 4 + wave;
        ushort2 lo; lo.x = f2bf(r[i].x); lo.y = f2bf(r[i].y);
        ushort2 hi; hi.x = f2bf(r[i].z); hi.y = f2bf(r[i].w);
        *(ushort2*)(&T[ch * TSTR + p0])     = lo;   // b32 writes, 2-way alias (free)
        *(ushort2*)(&T[ch * TSTR + p0 + 2]) = hi;
    }
    __syncthreads();

    // ---- store phase: px-pair assembly, conflict-free LDS reads ----
    const int maxpx = rem < 256 ? rem : 256;
    #pragma unroll
    for (int i = 0; i < 4; ++i) {
        const int idx  = i * 256 + tid;
        const int pair = idx >> 3;             // 0..127
        const int sub  = idx & 7;
        const int px   = 2 * pair;
        if (px < maxpx) {
            ushort2 w0 = *(const ushort2*)(&T[(sub * 8 + 0) * TSTR + px]);
            ushort2 w1 = *(const ushort2*)(&T[(sub * 8 + 1) * TSTR + px]);
            ushort2 w2 = *(const ushort2*)(&T[(sub * 8 + 2) * TSTR + px]);
            ushort2 w3 = *(const ushort2*)(&T[(sub * 8 + 3) * TSTR + px]);
            ushort2 w4 = *(const ushort2*)(&T[(sub * 8 + 4) * TSTR + px]);
            ushort2 w5 = *(const ushort2*)(&T[(sub * 8 + 5) * TSTR + px]);
            ushort2 w6 = *(const ushort2*)(&T[(sub * 8 + 6) * TSTR + px]);
            ushort2 w7 = *(const ushort2*)(&T[(sub * 8 + 7) * TSTR + px]);
            uint4 o0, o1;
            o0.x = (u32)w0.x | ((u32)w1.x << 16);
            o0.y = (u32)w2.x | ((u32)w3.x << 16);
            o0.z = (u32)w4.x | ((u32)w5.x << 16);
            o0.w = (u32)w6.x | ((u32)w7.x << 16);
            o1.x = (u32)w0.y | ((u32)w1.y << 16);
            o1.y = (u32)w2.y | ((u32)w3.y << 16);
            o1.z = (u32)w4.y | ((u32)w5.y << 16);
            o1.w = (u32)w6.y | ((u32)w7.y << 16);
            u16* dp = dst + ((size_t)(dstBase + b * HWsz + fbase + px)) * 256 + c0 + sub * 8;
            *(uint4*)dp = o0;
            if (px + 1 < maxpx) *(uint4*)(dp + 256) = o1;
        }
    }
}

// ---------------- gather: block owns (ROI n, 128 channels); LDS-transposed store ----
__global__ __launch_bounds__(256) void roi_gather(
    const u16* __restrict__ ws16, const RoiInfo2* __restrict__ info,
    float* __restrict__ out)
{
    __shared__ float lds[128 * 49];            // 25088 B
    const int g    = blockIdx.x;
    const int n    = blockIdx.y;
    const int tid  = threadIdx.x;
    const int lane = tid & 63;
    const int wave = tid >> 6;
    const RoiInfo2& ri = info[n];
    const int W = ri.W, base = ri.pxBase;
    const int c0 = g * 128;

    for (int cell = wave; cell < 49; cell += 4) {
        const int cu = __builtin_amdgcn_readfirstlane(cell);
        const int oy = cu / 7, ox = cu - oy * 7;
        float a0 = 0.0f, a1 = 0.0f;
        #pragma unroll
        for (int sy = 0; sy < 2; ++sy) {
            const int ei = oy * 2 + sy;
            const float wy0 = ri.wy0[ei], wy1 = ri.wy1[ei];
            const int rl = base + ri.yl[ei] * W;
            const int rh = base + ri.yh[ei] * W;
            #pragma unroll
            for (int sx = 0; sx < 2; ++sx) {
                const int ej = ox * 2 + sx;
                const float w00 = wy0 * ri.wx0[ej], w01 = wy0 * ri.wx1[ej];
                const float w10 = wy1 * ri.wx0[ej], w11 = wy1 * ri.wx1[ej];
                const int xl = ri.xl[ej], xh = ri.xh[ej];
                u32 u00 = ((const u32*)(ws16 + (size_t)(rl + xl) * 256 + c0))[lane];
                u32 u01 = ((const u32*)(ws16 + (size_t)(rl + xh) * 256 + c0))[lane];
                u32 u10 = ((const u32*)(ws16 + (size_t)(rh + xl) * 256 + c0))[lane];
                u32 u11 = ((const u32*)(ws16 + (size_t)(rh + xh) * 256 + c0))[lane];
                a0 += w00 * __uint_as_float(u00 << 16) + w01 * __uint_as_float(u01 << 16)
                    + w10 * __uint_as_float(u10 << 16) + w11 * __uint_as_float(u11 << 16);
                a1 += w00 * __uint_as_float(u00 & 0xffff0000u) + w01 * __uint_as_float(u01 & 0xffff0000u)
                    + w10 * __uint_as_float(u10 & 0xffff0000u) + w11 * __uint_as_float(u11 & 0xffff0000u);
            }
        }
        lds[(2 * lane) * 49 + cu]     = a0 * 0.25f;
        lds[(2 * lane + 1) * 49 + cu] = a1 * 0.25f;
    }
    __syncthreads();

    const float4* lv = (const float4*)lds;
    float4* ov = (float4*)(out + ((size_t)(n * C_ + c0)) * 49);
    for (int i = tid; i < 1568; i += 256) ov[i] = lv[i];
}

// ---------------- fallback: direct gather (if ws too small) ----------------
__global__ __launch_bounds__(256) void roi_direct(
    const float* __restrict__ f0, const float* __restrict__ f1,
    const float* __restrict__ f2, const float* __restrict__ f3,
    const float* __restrict__ boxes, float* __restrict__ out)
{
    const int total = B_ * R_ * C_ * OUTSZ * OUTSZ;
    int idx = blockIdx.x * blockDim.x + threadIdx.x;
    if (idx >= total) return;
    int ox = idx % 7, oy = (idx / 7) % 7, c = (idx / 49) % C_, n = idx / (49 * C_), b = n >> 8;
    const float* bx = boxes + (size_t)n * 4;
    float x1 = bx[0], y1 = bx[1], x2 = bx[2], y2 = bx[3];
    float lf = floorf(4.0f + log2f(sqrtf((x2 - x1) * (y2 - y1)) / 224.0f + 1e-8f));
    int lvl = (int)fminf(fmaxf(lf, 2.0f), 5.0f) - 2;
    const float scales[4] = {0.25f, 0.125f, 0.0625f, 0.03125f};
    const int sizes[4] = {200, 100, 50, 25};
    float scale = scales[lvl]; int HW = sizes[lvl];
    const float* fl = lvl == 0 ? f0 : lvl == 1 ? f1 : lvl == 2 ? f2 : f3;
    float fx1 = x1 * scale, fy1 = y1 * scale;
    float bw = fmaxf(x2 * scale - fx1, 1.0f) / 7.0f, bh = fmaxf(y2 * scale - fy1, 1.0f) / 7.0f;
    const float* plane = fl + ((size_t)(b * C_ + c)) * HW * HW;
    float lim = (float)HW, cap = lim - 1.0f, acc = 0.0f;
    #pragma unroll
    for (int sy = 0; sy < 2; sy++) {
        float yc = fy1 + bh * ((float)oy + ((float)sy + 0.5f) * 0.5f);
        bool vy = (yc > -1.0f) && (yc < lim);
        float ccy = fmaxf(yc, 0.0f), lowy = floorf(ccy);
        bool ey = lowy >= cap; lowy = fminf(lowy, cap);
        float highy = fminf(lowy + 1.0f, cap);
        float wfy = ey ? 0.0f : (ccy - lowy);
        int yl = (int)lowy, yh = (int)highy;
        #pragma unroll
        for (int sx = 0; sx < 2; sx++) {
            float xc = fx1 + bw * ((float)ox + ((float)sx + 0.5f) * 0.5f);
            bool vx = (xc > -1.0f) && (xc < lim);
            float ccx = fmaxf(xc, 0.0f), lowx = floorf(ccx);
            bool ex = lowx >= cap; lowx = fminf(lowx, cap);
            float highx = fminf(lowx + 1.0f, cap);
            float wfx = ex ? 0.0f : (ccx - lowx);
            int xl = (int)lowx, xh = (int)highx;
            if (vy && vx) {
                float v00 = plane[yl * HW + xl], v01 = plane[yl * HW + xh];
                float v10 = plane[yh * HW + xl], v11 = plane[yh * HW + xh];
                acc += (1.0f - wfy) * ((1.0f - wfx) * v00 + wfx * v01)
                     + wfy * ((1.0f - wfx) * v10 + wfx * v11);
            }
        }
    }
    out[idx] = acc * 0.25f;
}

extern "C" void kernel_launch(void* const* d_in, const int* in_sizes, int n_in,
                              void* d_out, int out_size, void* d_ws, size_t ws_size,
                              hipStream_t stream) {
    const float* f0    = (const float*)d_in[0];
    const float* f1    = (const float*)d_in[1];
    const float* f2    = (const float*)d_in[2];
    const float* f3    = (const float*)d_in[3];
    const float* boxes = (const float*)d_in[4];
    float* out = (float*)d_out;

    if (ws_size < WS_NEEDED) {
        const int total = B_ * R_ * C_ * OUTSZ * OUTSZ;
        roi_direct<<<(total + 255) / 256, 256, 0, stream>>>(f0, f1, f2, f3, boxes, out);
        return;
    }

    RoiInfo2* info = (RoiInfo2*)((char*)d_ws + WS_INFO_OFF);
    u16*      nhwc = (u16*)((char*)d_ws + WS_NHWC_OFF);

    roi_prep<<<dim3(2), 256, 0, stream>>>(boxes, info);
    nhwc_cast<<<dim3(210, 4, 2), 256, 0, stream>>>(f0, f1, f2, f3, nhwc);
    roi_gather<<<dim3(2, N_), 256, 0, stream>>>(nhwc, info, out);
}